// Round 4
// baseline (61.237 us; speedup 1.0000x reference)
//
#include <hip/hip_runtime.h>
#include <hip/hip_bf16.h>

// Problem constants (fixed by reference setup_inputs)
#define BB 4
#define LL 4096
#define MM 1024
#define DD 2048
#define SEG 32
#define SM 32          // MM / SEG
#define SEGSHIFT 5

typedef float f32x4 __attribute__((ext_vector_type(4)));

// ---------------------------------------------------------------------------
// Kernel A: per-batch prep.
//  - block-wide cumsum of boundary_mask over L=4096 (1024 thr x 4 elems)
//  - scatter clipped p into p_chunked (stable partition: boundary first)
//  - chunk_idx[b,l] = clip(incl_cumsum-1, 0, M-1)
//  - Pseg[b,s] = product of a[t] over segment s (a[0]=0, else 1-p[t])
// ---------------------------------------------------------------------------
__global__ __launch_bounds__(1024) void prep_kernel(
    const float* __restrict__ bprob,   // (B, L, 2)
    const int*   __restrict__ bmask,   // (B, L) 0/1
    float* __restrict__ p_chunked,     // (B, M)
    int*   __restrict__ chunk_idx,     // (B, L)
    float* __restrict__ Pseg)          // (B, SEG)
{
    const int b   = blockIdx.x;
    const int tid = threadIdx.x;
    const int lane = tid & 63;
    const int wid  = tid >> 6;

    __shared__ int wsum[16];
    __shared__ int s_total;

    // ---- load 4 mask values per thread (contiguous int4) ----
    int4 mv = reinterpret_cast<const int4*>(bmask + b * LL)[tid];
    int ms[4] = { mv.x, mv.y, mv.z, mv.w };
    int s = ms[0] + ms[1] + ms[2] + ms[3];

    // wave inclusive scan of per-thread sums
    int v = s;
    #pragma unroll
    for (int off = 1; off < 64; off <<= 1) {
        int u = __shfl_up(v, off, 64);
        if (lane >= off) v += u;
    }
    if (lane == 63) wsum[wid] = v;
    __syncthreads();
    if (tid == 0) {
        int acc = 0;
        #pragma unroll
        for (int w = 0; w < 16; ++w) { int t = wsum[w]; wsum[w] = acc; acc += t; }
        s_total = acc;
    }
    __syncthreads();

    const int NB = s_total;                 // total boundary tokens in batch
    int e = (v - s) + wsum[wid];            // exclusive prefix for first elem

    const int base_l = tid * 4;
    #pragma unroll
    for (int j = 0; j < 4; ++j) {
        int l = base_l + j;
        int m = ms[j];
        int incl = e + m;
        int ci = incl - 1;
        ci = ci < 0 ? 0 : (ci > MM - 1 ? MM - 1 : ci);
        chunk_idx[b * LL + l] = ci;
        int pos = m ? e : (NB + (l - e));   // stable partition position
        if (pos < MM) {
            float p = bprob[((size_t)b * LL + l) * 2 + 1];
            p = fminf(fmaxf(p, 1e-4f), 1.0f - 1e-4f);
            p_chunked[b * MM + pos] = p;
        }
        e = incl;
    }
    __syncthreads();

    // ---- per-segment products over 32-wide segments: t = tid ----
    {
        int t = tid;
        float p = p_chunked[b * MM + t];
        float a = (t == 0) ? 0.0f : (1.0f - p);
        float pr = a;
        #pragma unroll
        for (int off = 1; off < 32; off <<= 1) {
            float u = __shfl_up(pr, off, 32);   // within 32-wide subgroups
            if ((t & 31) >= off) pr *= u;
        }
        if ((t & 31) == 31) Pseg[b * SEG + (t >> SEGSHIFT)] = pr;
    }
}

// ---------------------------------------------------------------------------
// Kernel B (pass 1): per-segment scan, emitting ONLY the segment-end value.
// grid = (D/512, SEG, B) = 512 blocks, block = 256, float2 per thread.
// ---------------------------------------------------------------------------
__global__ __launch_bounds__(256) void seglast_kernel(
    const float* __restrict__ x,          // (B, M, D)
    const float* __restrict__ p_chunked,  // (B, M)
    float* __restrict__ seglast)          // (B, SEG, D)
{
    const int d0  = blockIdx.x * 512 + threadIdx.x * 2;
    const int seg = blockIdx.y;
    const int b   = blockIdx.z;
    const int t0  = seg * SM;

    __shared__ float sp[SM];
    if (threadIdx.x < SM) sp[threadIdx.x] = p_chunked[b * MM + t0 + threadIdx.x];
    __syncthreads();

    size_t base = ((size_t)b * MM + t0) * DD + d0;

    float2 prev = make_float2(0.0f, 0.0f);
    #pragma unroll
    for (int i = 0; i < SM; ++i) {
        float p = sp[i];
        bool first = (seg == 0) && (i == 0);
        float ac = first ? 0.0f : (1.0f - p);
        float bc = first ? 1.0f : p;
        float2 xt = *reinterpret_cast<const float2*>(x + base + (size_t)i * DD);
        prev.x = fmaf(ac, prev.x, bc * xt.x);
        prev.y = fmaf(ac, prev.y, bc * xt.y);
    }
    *reinterpret_cast<float2*>(seglast + ((size_t)b * SEG + seg) * DD + d0) = prev;
}

// ---------------------------------------------------------------------------
// Kernel C (pass 2): final scan. Each block inline-computes its carry-in
// from seglast + Pseg (tiny L2 reads), re-scans x (LLC-hot) with the true
// carry, and writes the CORRECTED y. No later fix-up needed.
// ---------------------------------------------------------------------------
__global__ __launch_bounds__(256) void scan_final_kernel(
    const float* __restrict__ x,          // (B, M, D)
    const float* __restrict__ p_chunked,  // (B, M)
    const float* __restrict__ seglast,    // (B, SEG, D)
    const float* __restrict__ Pseg,       // (B, SEG)
    float* __restrict__ y)                // (B, M, D)
{
    const int d0  = blockIdx.x * 512 + threadIdx.x * 2;
    const int seg = blockIdx.y;
    const int b   = blockIdx.z;
    const int t0  = seg * SM;

    __shared__ float sp[SM];
    if (threadIdx.x < SM) sp[threadIdx.x] = p_chunked[b * MM + t0 + threadIdx.x];
    __syncthreads();

    // carry-in: run the inter-segment recurrence over segments 0..seg-1
    float2 prev = make_float2(0.0f, 0.0f);
    #pragma unroll 8
    for (int s = 0; s < seg; ++s) {
        float Pf = Pseg[b * SEG + s];     // uniform scalar
        float2 lastv = *reinterpret_cast<const float2*>(
            seglast + ((size_t)b * SEG + s) * DD + d0);
        prev.x = fmaf(Pf, prev.x, lastv.x);
        prev.y = fmaf(Pf, prev.y, lastv.y);
    }

    size_t base = ((size_t)b * MM + t0) * DD + d0;

    #pragma unroll
    for (int i = 0; i < SM; ++i) {
        float p = sp[i];
        bool first = (seg == 0) && (i == 0);
        float ac = first ? 0.0f : (1.0f - p);
        float bc = first ? 1.0f : p;
        float2 xt = *reinterpret_cast<const float2*>(x + base + (size_t)i * DD);
        prev.x = fmaf(ac, prev.x, bc * xt.x);
        prev.y = fmaf(ac, prev.y, bc * xt.y);
        *reinterpret_cast<float2*>(y + base + (size_t)i * DD) = prev;
    }
}

// ---------------------------------------------------------------------------
// Kernel D: pure gather. out[b,l,:] = y[b, chunk_idx[b,l], :]
// grid = (L, B), block = 256, f32x4; nt stores (out is write-once).
// ---------------------------------------------------------------------------
__global__ __launch_bounds__(256) void gather_kernel(
    const float* __restrict__ y,
    const int*   __restrict__ chunk_idx,
    float* __restrict__ out)              // (B, L, D)
{
    const int l = blockIdx.x;
    const int b = blockIdx.y;
    const int t = chunk_idx[b * LL + l];

    const f32x4* yrow = reinterpret_cast<const f32x4*>(y + ((size_t)b * MM + t) * DD);
    f32x4* orow       = reinterpret_cast<f32x4*>(out + ((size_t)b * LL + l) * DD);

    const int tid = threadIdx.x;
    #pragma unroll
    for (int k = 0; k < 2; ++k) {
        int i = tid + k * 256;            // 512 vec4 per row
        f32x4 v = yrow[i];
        __builtin_nontemporal_store(v, &orow[i]);
    }
}

// ---------------------------------------------------------------------------
extern "C" void kernel_launch(void* const* d_in, const int* in_sizes, int n_in,
                              void* d_out, int out_size, void* d_ws, size_t ws_size,
                              hipStream_t stream) {
    const float* x     = (const float*)d_in[0];   // chunked_states (B,M,D) f32
    const float* bprob = (const float*)d_in[1];   // boundary_prob  (B,L,2) f32
    const int*   bmask = (const int*)d_in[2];     // boundary_mask  (B,L) int

    float* out = (float*)d_out;

    // workspace layout
    float* y         = (float*)d_ws;                          // B*M*D
    float* p_chunked = y + (size_t)BB * MM * DD;              // B*M
    float* Pseg      = p_chunked + BB * MM;                   // B*SEG
    float* seglast   = Pseg + BB * SEG;                       // B*SEG*D
    int*   chunk_idx = (int*)(seglast + (size_t)BB * SEG * DD); // B*L

    prep_kernel<<<BB, 1024, 0, stream>>>(bprob, bmask, p_chunked, chunk_idx, Pseg);
    seglast_kernel<<<dim3(DD / 512, SEG, BB), 256, 0, stream>>>(x, p_chunked, seglast);
    scan_final_kernel<<<dim3(DD / 512, SEG, BB), 256, 0, stream>>>(x, p_chunked, seglast, Pseg, y);
    gather_kernel<<<dim3(LL, BB), 256, 0, stream>>>(y, chunk_idx, out);
}